// Round 3
// baseline (57239.667 us; speedup 1.0000x reference)
//
#include <hip/hip_runtime.h>

// Decoder: PreNet(2xLinear+ReLU) -> 3x LSTM(768) with residuals -> proj(768->128)
// B=16, T=1000, H=768. All fp32.
//
//  - gemm_tn: generic fp32 C[M,N] = act(A[M,K] @ W[N,K]^T + b1 + b2 (+C))
//    128x128 tile, BK=32, 8x8 reg tile. Rows decoded as (t,b): addr = (m>>4)*sa_t + (m&15)*sa_b.
//  - lstm_scan: persistent kernel, 192 blocks x 256 thr (<=256 CUs -> co-resident).
//    W_hh in registers (4 rows x 12 k per thread), h staged global->LDS each step,
//    64-lane butterfly reduce-scatter, gate math on wave 0, custom 2-level grid barrier.
//  - xg precomputed per 256-step chunk (chunks 256/256/256/232) to bound ws at ~116MB.
//
// ws layout (floats): s[12288000] | m2[4096000] | xg[12582912] | hbuf[24576] | cbuf[12288] | flags

#define NBLK 192

// ---------------------------------------------------------------------------
// Generic tiled fp32 GEMM: C = act(A @ W^T + biases (+ C))
// ---------------------------------------------------------------------------
__global__ __launch_bounds__(256, 2) void gemm_tn(
    const float* __restrict__ A, long sa_t, long sa_b,
    const float* __restrict__ W, long ldw,
    const float* __restrict__ b1, const float* __restrict__ b2,
    float* __restrict__ C, long sc_t, long sc_b,
    int K, int relu, int beta)
{
    __shared__ __align__(16) float At[32][132];
    __shared__ __align__(16) float Wt[32][132];
    const int tid = threadIdx.x;
    const int bm = blockIdx.x << 7;
    const int bn = blockIdx.y << 7;
    const int tx = tid & 15, ty = tid >> 4;

    float acc[8][8];
#pragma unroll
    for (int i = 0; i < 8; ++i)
#pragma unroll
        for (int j = 0; j < 8; ++j) acc[i][j] = 0.f;

    const int row_s = tid >> 3;        // 0..31
    const int kq    = (tid & 7) << 2;  // 0,4,..,28

    for (int k0 = 0; k0 < K; k0 += 32) {
#pragma unroll
        for (int i = 0; i < 4; ++i) {
            const int row = row_s + (i << 5);      // 0..127
            const int m = bm + row;
            const float* ap = A + (long)(m >> 4) * sa_t + (long)(m & 15) * sa_b + k0 + kq;
            float4 av = *(const float4*)ap;
            const int n = bn + row;
            const float* wp = W + (long)n * ldw + k0 + kq;
            float4 wv = *(const float4*)wp;
            At[kq + 0][row] = av.x; At[kq + 1][row] = av.y;
            At[kq + 2][row] = av.z; At[kq + 3][row] = av.w;
            Wt[kq + 0][row] = wv.x; Wt[kq + 1][row] = wv.y;
            Wt[kq + 2][row] = wv.z; Wt[kq + 3][row] = wv.w;
        }
        __syncthreads();
#pragma unroll
        for (int kk = 0; kk < 32; ++kk) {
            float a[8], w[8];
            *(float4*)&a[0] = *(const float4*)&At[kk][ty << 3];
            *(float4*)&a[4] = *(const float4*)&At[kk][(ty << 3) + 4];
            *(float4*)&w[0] = *(const float4*)&Wt[kk][tx << 3];
            *(float4*)&w[4] = *(const float4*)&Wt[kk][(tx << 3) + 4];
#pragma unroll
            for (int i = 0; i < 8; ++i)
#pragma unroll
                for (int j = 0; j < 8; ++j) acc[i][j] += a[i] * w[j];
        }
        __syncthreads();
    }

#pragma unroll
    for (int i = 0; i < 8; ++i) {
        const int m = bm + (ty << 3) + i;
        const long crow = (long)(m >> 4) * sc_t + (long)(m & 15) * sc_b;
#pragma unroll
        for (int j4 = 0; j4 < 8; j4 += 4) {
            const int n = bn + (tx << 3) + j4;
            float4 v = make_float4(acc[i][j4], acc[i][j4 + 1], acc[i][j4 + 2], acc[i][j4 + 3]);
            if (b1) { float4 t = *(const float4*)(b1 + n); v.x += t.x; v.y += t.y; v.z += t.z; v.w += t.w; }
            if (b2) { float4 t = *(const float4*)(b2 + n); v.x += t.x; v.y += t.y; v.z += t.z; v.w += t.w; }
            if (beta) { float4 t = *(const float4*)(C + crow + n); v.x += t.x; v.y += t.y; v.z += t.z; v.w += t.w; }
            if (relu) { v.x = fmaxf(v.x, 0.f); v.y = fmaxf(v.y, 0.f); v.z = fmaxf(v.z, 0.f); v.w = fmaxf(v.w, 0.f); }
            *(float4*)(C + crow + n) = v;
        }
    }
}

// ---------------------------------------------------------------------------
// LSTM scan: persistent kernel over [t0,t1).
// Block owns 4 h-columns. Wave g = gate g; lane lid covers k = lid*4+j + 256*i2.
// Butterfly reduce-scatter leaves lane l with the dot for (c=l>>4, b=l&15).
// ---------------------------------------------------------------------------
__device__ __forceinline__ float sigm_(float x) { return 1.f / (1.f + expf(-x)); }

__global__ __launch_bounds__(256, 1) void lstm_scan(
    const float* __restrict__ xg, float* __restrict__ s,
    float* __restrict__ hbuf, float* __restrict__ cbuf,
    const float* __restrict__ w_hh, unsigned* __restrict__ flags,
    int t0, int t1, int resid)
{
    __shared__ __align__(16) float h_lds[12288];   // [16][768]
    __shared__ __align__(16) float gbuf[256];      // gate g value for (c,b) at g*64 + (c*16+b)
    const int tid = threadIdx.x;
    const int g   = tid >> 6;    // wave id = gate (i,f,g,o)
    const int lid = tid & 63;
    const int bid = blockIdx.x;
    const int col = (bid << 2) + (lid >> 4);  // wave-0 output column
    const int bl  = lid & 15;                 // wave-0 output batch

    // W_hh fragment: Wf[c][i2] = w_hh[g*768 + bid*4 + c][lid*4 + i2*256 .. +3]
    float4 Wf[4][3];
#pragma unroll
    for (int c = 0; c < 4; ++c) {
        const float* wr = w_hh + (size_t)(g * 768 + (bid << 2) + c) * 768 + (lid << 2);
#pragma unroll
        for (int i2 = 0; i2 < 3; ++i2) Wf[c][i2] = *(const float4*)(wr + i2 * 256);
    }

    float c_reg = 0.f;
    if (g == 0) c_reg = cbuf[bl * 768 + col];

    for (int t = t0; t < t1; ++t) {
        const int tloc = t - t0;

        // wave 0: issue xg / s_old loads early (consumed ~2000cy later)
        float xgv[4] = {0.f, 0.f, 0.f, 0.f};
        float s_old = 0.f;
        if (g == 0) {
            const float* xp = xg + (size_t)(tloc * 16 + bl) * 3072 + col;
#pragma unroll
            for (int q = 0; q < 4; ++q) xgv[q] = xp[q * 768];
            if (resid) s_old = s[(size_t)(t * 16 + bl) * 768 + col];
        }

        // stage h (parity buffer keyed on absolute t) global -> LDS, coalesced
        const float4* hin = (const float4*)(hbuf + (t & 1) * 12288);
        float4 hv[12];
#pragma unroll
        for (int i = 0; i < 12; ++i) hv[i] = hin[tid + (i << 8)];
#pragma unroll
        for (int i = 0; i < 12; ++i) ((float4*)h_lds)[tid + (i << 8)] = hv[i];
        __syncthreads();

        // partial dots: v[c*16+b] over this lane's 12 k values
        float v[64];
#pragma unroll
        for (int i = 0; i < 64; ++i) v[i] = 0.f;
#pragma unroll
        for (int b = 0; b < 16; ++b) {
            const float* hp = h_lds + b * 768 + (lid << 2);
            float4 h0 = *(const float4*)hp;
            float4 h1 = *(const float4*)(hp + 256);
            float4 h2 = *(const float4*)(hp + 512);
#pragma unroll
            for (int c = 0; c < 4; ++c) {
                float a = v[c * 16 + b];
                a += Wf[c][0].x * h0.x + Wf[c][0].y * h0.y + Wf[c][0].z * h0.z + Wf[c][0].w * h0.w;
                a += Wf[c][1].x * h1.x + Wf[c][1].y * h1.y + Wf[c][1].z * h1.z + Wf[c][1].w * h1.w;
                a += Wf[c][2].x * h2.x + Wf[c][2].y * h2.y + Wf[c][2].z * h2.z + Wf[c][2].w * h2.w;
                v[c * 16 + b] = a;
            }
        }

        // butterfly reduce-scatter across 64 lanes: lane l ends with full dot l
#pragma unroll
        for (int d = 32; d >= 1; d >>= 1) {
            const bool up = (lid & d) != 0;
#pragma unroll
            for (int j = 0; j < d; ++j) {
                float mine  = up ? v[j + d] : v[j];
                float other = up ? v[j]     : v[j + d];
                v[j] = mine + __shfl_xor(other, d, 64);
            }
        }
        gbuf[(g << 6) + lid] = v[0];
        __syncthreads();

        if (g == 0) {
            float gi = gbuf[lid]        + xgv[0];
            float gf = gbuf[64 + lid]   + xgv[1];
            float gc = gbuf[128 + lid]  + xgv[2];
            float go = gbuf[192 + lid]  + xgv[3];
            float fi = sigm_(gi), ff = sigm_(gf), tc = tanhf(gc), fo = sigm_(go);
            float cn = ff * c_reg + fi * tc;
            c_reg = cn;
            float hn = fo * tanhf(cn);
            hbuf[((t + 1) & 1) * 12288 + bl * 768 + col] = hn;
            s[(size_t)(t * 16 + bl) * 768 + col] = resid ? (s_old + hn) : hn;
        }

        // ---- grid barrier (epoch = tloc+1; flags zeroed before launch) ----
        __syncthreads();   // all waves' global stores complete (vmcnt0) before release
        if (tid == 0) {
            __builtin_amdgcn_fence(__ATOMIC_RELEASE, "agent");  // writeback local L2
            const unsigned e = (unsigned)(tloc + 1);
            unsigned a = __hip_atomic_fetch_add(&flags[(bid >> 5) << 4], 1u,
                                                __ATOMIC_RELAXED, __HIP_MEMORY_SCOPE_AGENT);
            if (a == e * 32u - 1u) {  // last of my 32-block group this epoch
                unsigned r = __hip_atomic_fetch_add(&flags[96], 1u,
                                                    __ATOMIC_RELAXED, __HIP_MEMORY_SCOPE_AGENT);
                if (r == e * 6u - 1u)  // last group
                    __hip_atomic_store(&flags[112], e, __ATOMIC_RELEASE, __HIP_MEMORY_SCOPE_AGENT);
            }
            while (__hip_atomic_load(&flags[112], __ATOMIC_RELAXED, __HIP_MEMORY_SCOPE_AGENT) < e)
                __builtin_amdgcn_s_sleep(1);
        }
        __syncthreads();
        // every wave invalidates caches before reading the new-parity h
        __builtin_amdgcn_fence(__ATOMIC_ACQUIRE, "agent");
    }

    if (g == 0) cbuf[bl * 768 + col] = c_reg;
}

// ---------------------------------------------------------------------------
extern "C" void kernel_launch(void* const* d_in, const int* in_sizes, int n_in,
                              void* d_out, int out_size, void* d_ws, size_t ws_size,
                              hipStream_t stream)
{
    const float* x    = (const float*)d_in[0];
    const float* mels = (const float*)d_in[1];
    const float* pw1  = (const float*)d_in[2];
    const float* pb1  = (const float*)d_in[3];
    const float* pw2  = (const float*)d_in[4];
    const float* pb2  = (const float*)d_in[5];
    const float* w_ih[3] = {(const float*)d_in[6],  (const float*)d_in[10], (const float*)d_in[14]};
    const float* w_hh[3] = {(const float*)d_in[7],  (const float*)d_in[11], (const float*)d_in[15]};
    const float* b_ih[3] = {(const float*)d_in[8],  (const float*)d_in[12], (const float*)d_in[16]};
    const float* b_hh[3] = {(const float*)d_in[9],  (const float*)d_in[13], (const float*)d_in[17]};
    const float* projw = (const float*)d_in[18];
    float* out = (float*)d_out;

    float* s    = (float*)d_ws;            // [1000][16][768]
    float* m2   = s + 12288000;            // [16000][256] (t,b)-rows
    float* xgb  = m2 + 4096000;            // [256][16][3072] chunk buffer
    float* hbuf = xgb + 12582912;          // [2][16][768]
    float* cbuf = hbuf + 24576;            // [16][768]
    unsigned* flags = (unsigned*)(cbuf + 12288);
    float* m1 = xgb;                       // prenet intermediate aliases xg buffer

    // PreNet: m1 = relu(mels@pw1^T + pb1); m2 = relu(m1@pw2^T + pb2)
    gemm_tn<<<dim3(125, 2), 256, 0, stream>>>(mels, 128, 128000, pw1, 128, pb1, nullptr,
                                              m1, 4096, 256, 128, 1, 0);
    gemm_tn<<<dim3(125, 2), 256, 0, stream>>>(m1, 4096, 256, pw2, 256, pb2, nullptr,
                                              m2, 4096, 256, 256, 1, 0);

    const int t0s[4] = {0, 256, 512, 768};
    const int tcs[4] = {256, 256, 256, 232};

    for (int L = 0; L < 3; ++L) {
        hipMemsetAsync(hbuf, 0, (size_t)(24576 + 12288) * sizeof(float), stream);  // h=0, c=0
        for (int ch = 0; ch < 4; ++ch) {
            int t0 = t0s[ch], tc = tcs[ch];
            int gm = (tc * 16) / 128;  // 32 or 29
            if (L == 0) {
                // xg = [x | m2] @ w_ih1^T + b_ih1 + b_hh1  (split-K across the concat)
                gemm_tn<<<dim3(gm, 24), 256, 0, stream>>>(x + (size_t)t0 * 512, 512, 512000,
                                                          w_ih[0], 768, b_ih[0], b_hh[0],
                                                          xgb, 49152, 3072, 512, 0, 0);
                gemm_tn<<<dim3(gm, 24), 256, 0, stream>>>(m2 + (size_t)t0 * 4096, 4096, 256,
                                                          w_ih[0] + 512, 768, nullptr, nullptr,
                                                          xgb, 49152, 3072, 256, 0, 1);
            } else {
                gemm_tn<<<dim3(gm, 24), 256, 0, stream>>>(s + (size_t)t0 * 12288, 12288, 768,
                                                          w_ih[L], 768, b_ih[L], b_hh[L],
                                                          xgb, 49152, 3072, 768, 0, 0);
            }
            hipMemsetAsync(flags, 0, 512, stream);
            int t1 = t0 + tc;
            int resid = (L > 0) ? 1 : 0;
            // Plain launch: 192 blocks <= 256 CUs and nothing else co-scheduled on the
            // device during graph replay -> all blocks co-resident; barrier is safe.
            lstm_scan<<<dim3(NBLK), 256, 0, stream>>>(xgb, s, hbuf, cbuf, w_hh[L], flags,
                                                      t0, t1, resid);
        }
    }

    // out[b][t][:] = s @ proj_w^T
    gemm_tn<<<dim3(125, 1), 256, 0, stream>>>(s, 12288, 768, projw, 768, nullptr, nullptr,
                                              out, 128, 128000, 768, 0, 0);
}

// Round 5
// 56890.790 us; speedup vs baseline: 1.0061x; 1.0061x over previous
//
#include <hip/hip_runtime.h>

// Decoder: PreNet(2xLinear+ReLU) -> 3x LSTM(768) with residuals -> proj(768->128)
// B=16, T=1000, H=768. All fp32.
//
//  - gemm_tn: fp32 C[M,N] = act(A @ W^T + b1 + b2 (+C)). 128x128 tile, BK=32,
//    8x8 reg tile (cols tx*4+{0,64}), XOR-swizzled LDS (no pad, conflict-free).
//  - lstm_scan: persistent kernel, 192 blocks x 256 thr. W_hh in registers,
//    h staged via global_load_lds, butterfly reduce-scatter with LITERAL stage
//    widths (BFLY macro -> all v[] indices static -> no scratch), 2-level grid barrier.
//  - xg per 256-step chunk.
//
// ws layout (floats): s[12288000] | m2[4096000] | xg[12582912] | hbuf[24576] | cbuf[12288] | flags

#define NBLK 192

// ---------------------------------------------------------------------------
// GEMM: C = act(A @ W^T + biases (+C)); A/C rows decoded as (t,b).
// LDS swizzle: logical (k, col) stored at [k][col ^ ((k>>2 & 7)<<2)], stride 128.
// ---------------------------------------------------------------------------
__global__ __launch_bounds__(256, 2) void gemm_tn(
    const float* __restrict__ A, int sa_t, int sa_b,
    const float* __restrict__ W, int ldw,
    const float* __restrict__ b1, const float* __restrict__ b2,
    float* __restrict__ C, int sc_t, int sc_b,
    int K, int relu, int beta)
{
    __shared__ __align__(16) float At[32][128];
    __shared__ __align__(16) float Wt[32][128];
    const int tid = threadIdx.x;
    const int bm = blockIdx.x << 7;
    const int bn = blockIdx.y << 7;
    const int tx = tid & 15, ty = tid >> 4;

    float acc[8][8];
#pragma unroll
    for (int i = 0; i < 8; ++i)
#pragma unroll
        for (int j = 0; j < 8; ++j) acc[i][j] = 0.f;

    const int row_s = tid >> 3;        // 0..31
    const int kq    = (tid & 7) << 2;  // 0,4,..,28
    const int qw    = kq >> 2;         // 0..7 (swizzle index for this thread's k-quad)

    for (int k0 = 0; k0 < K; k0 += 32) {
#pragma unroll
        for (int i = 0; i < 4; ++i) {
            const int row = row_s + (i << 5);      // 0..127
            const int m = bm + row;
            const float* ap = A + (size_t)(m >> 4) * sa_t + (m & 15) * sa_b + k0 + kq;
            float4 av = *(const float4*)ap;
            const int n = bn + row;
            const float* wp = W + (size_t)n * ldw + k0 + kq;
            float4 wv = *(const float4*)wp;
            const int p = row ^ (qw << 2);         // swizzled column
            At[kq + 0][p] = av.x; At[kq + 1][p] = av.y;
            At[kq + 2][p] = av.z; At[kq + 3][p] = av.w;
            Wt[kq + 0][p] = wv.x; Wt[kq + 1][p] = wv.y;
            Wt[kq + 2][p] = wv.z; Wt[kq + 3][p] = wv.w;
        }
        __syncthreads();
#pragma unroll
        for (int kk = 0; kk < 32; ++kk) {
            const int sw = ((kk >> 2) & 7) << 2;
            float a[8], w[8];
            const int ab = (ty << 3) ^ sw;         // rows ty*8..+3 (swizzled base)
            *(float4*)&a[0] = *(const float4*)&At[kk][ab];
            *(float4*)&a[4] = *(const float4*)&At[kk][ab ^ 4];
            const int wb = (tx << 2) ^ sw;         // cols tx*4..+3
            *(float4*)&w[0] = *(const float4*)&Wt[kk][wb];
            *(float4*)&w[4] = *(const float4*)&Wt[kk][64 + wb];
#pragma unroll
            for (int i = 0; i < 8; ++i)
#pragma unroll
                for (int j = 0; j < 8; ++j) acc[i][j] += a[i] * w[j];
        }
        __syncthreads();
    }

    // cols: j<4 -> bn + tx*4 + j ; j>=4 -> bn + 64 + tx*4 + (j-4)
#pragma unroll
    for (int i = 0; i < 8; ++i) {
        const int m = bm + (ty << 3) + i;
        const size_t crow = (size_t)(m >> 4) * sc_t + (m & 15) * sc_b;
#pragma unroll
        for (int jg = 0; jg < 2; ++jg) {
            const int n = bn + (jg << 6) + (tx << 2);
            const int j0 = jg << 2;
            float4 v = make_float4(acc[i][j0], acc[i][j0 + 1], acc[i][j0 + 2], acc[i][j0 + 3]);
            if (b1) { float4 t = *(const float4*)(b1 + n); v.x += t.x; v.y += t.y; v.z += t.z; v.w += t.w; }
            if (b2) { float4 t = *(const float4*)(b2 + n); v.x += t.x; v.y += t.y; v.z += t.z; v.w += t.w; }
            if (beta) { float4 t = *(const float4*)(C + crow + n); v.x += t.x; v.y += t.y; v.z += t.z; v.w += t.w; }
            if (relu) { v.x = fmaxf(v.x, 0.f); v.y = fmaxf(v.y, 0.f); v.z = fmaxf(v.z, 0.f); v.w = fmaxf(v.w, 0.f); }
            *(float4*)(C + crow + n) = v;
        }
    }
}

// ---------------------------------------------------------------------------
// LSTM scan (persistent). Butterfly stages use LITERAL d so v[] stays in VGPRs.
// ---------------------------------------------------------------------------
__device__ __forceinline__ float sigm_(float x) { return 1.f / (1.f + expf(-x)); }

#define BFLY(d)                                                         \
    do {                                                                \
        _Pragma("unroll")                                               \
        for (int j = 0; j < (d); ++j) {                                 \
            float mine  = (lid & (d)) ? v[j + (d)] : v[j];              \
            float other = (lid & (d)) ? v[j]       : v[j + (d)];        \
            v[j] = mine + __shfl_xor(other, (d), 64);                   \
        }                                                               \
    } while (0)

__global__ __launch_bounds__(256, 1) void lstm_scan(
    const float* __restrict__ xg, float* __restrict__ s,
    float* __restrict__ hbuf, float* __restrict__ cbuf,
    const float* __restrict__ w_hh, unsigned* __restrict__ flags,
    int t0, int t1, int resid)
{
    __shared__ __align__(16) float h_lds[12288];   // [16][768]
    __shared__ __align__(16) float gbuf[256];
    const int tid = threadIdx.x;
    const int g   = tid >> 6;    // wave id = gate (i,f,g,o)
    const int lid = tid & 63;
    const int bid = blockIdx.x;
    const int col = (bid << 2) + (lid >> 4);  // wave-0 output column
    const int bl  = lid & 15;                 // wave-0 output batch

    // W_hh fragment: Wf[c][i2] = w_hh[g*768 + bid*4 + c][lid*4 + i2*256 .. +3]
    float4 Wf[4][3];
#pragma unroll
    for (int c = 0; c < 4; ++c) {
        const float* wr = w_hh + (size_t)(g * 768 + (bid << 2) + c) * 768 + (lid << 2);
#pragma unroll
        for (int i2 = 0; i2 < 3; ++i2) Wf[c][i2] = *(const float4*)(wr + i2 * 256);
    }

    float c_reg = 0.f;
    if (g == 0) c_reg = cbuf[bl * 768 + col];

    for (int t = t0; t < t1; ++t) {
        const int tloc = t - t0;

        // wave 0: issue xg / s_old loads early
        float xgv[4] = {0.f, 0.f, 0.f, 0.f};
        float s_old = 0.f;
        if (g == 0) {
            const float* xp = xg + (size_t)(tloc * 16 + bl) * 3072 + col;
#pragma unroll
            for (int q = 0; q < 4; ++q) xgv[q] = xp[q * 768];
            if (resid) s_old = s[(size_t)(t * 16 + bl) * 768 + col];
        }

        // stage h (parity on absolute t) global -> LDS
        const float* hin = hbuf + (t & 1) * 12288;
#if defined(__has_builtin) && __has_builtin(__builtin_amdgcn_global_load_lds)
        {
            const int wv = tid >> 6;
#pragma unroll
            for (int i = 0; i < 12; ++i) {
                const float* gp = hin + (tid << 2) + (i << 10);     // per-lane global addr
                float* lp = h_lds + (wv << 8) + (i << 10);          // wave-uniform LDS base
                __builtin_amdgcn_global_load_lds(
                    (const __attribute__((address_space(1))) unsigned int*)gp,
                    (__attribute__((address_space(3))) unsigned int*)lp, 16, 0, 0);
            }
        }
#else
        {
            float4 hv[12];
#pragma unroll
            for (int i = 0; i < 12; ++i) hv[i] = ((const float4*)hin)[tid + (i << 8)];
#pragma unroll
            for (int i = 0; i < 12; ++i) ((float4*)h_lds)[tid + (i << 8)] = hv[i];
        }
#endif
        __syncthreads();   // waits vmcnt(0): global_load_lds complete

        // partial dots: v[c*16+b] over this lane's 12 k values
        float v[64];
#pragma unroll
        for (int i = 0; i < 64; ++i) v[i] = 0.f;
#pragma unroll
        for (int b = 0; b < 16; ++b) {
            const float* hp = h_lds + b * 768 + (lid << 2);
            float4 h0 = *(const float4*)hp;
            float4 h1 = *(const float4*)(hp + 256);
            float4 h2 = *(const float4*)(hp + 512);
#pragma unroll
            for (int c = 0; c < 4; ++c) {
                float a = v[c * 16 + b];
                a += Wf[c][0].x * h0.x + Wf[c][0].y * h0.y + Wf[c][0].z * h0.z + Wf[c][0].w * h0.w;
                a += Wf[c][1].x * h1.x + Wf[c][1].y * h1.y + Wf[c][1].z * h1.z + Wf[c][1].w * h1.w;
                a += Wf[c][2].x * h2.x + Wf[c][2].y * h2.y + Wf[c][2].z * h2.z + Wf[c][2].w * h2.w;
                v[c * 16 + b] = a;
            }
        }

        // butterfly reduce-scatter, literal stage widths (static v[] indices)
        BFLY(32); BFLY(16); BFLY(8); BFLY(4); BFLY(2); BFLY(1);
        gbuf[(g << 6) + lid] = v[0];
        __syncthreads();

        if (g == 0) {
            float gi = gbuf[lid]        + xgv[0];
            float gf = gbuf[64 + lid]   + xgv[1];
            float gc = gbuf[128 + lid]  + xgv[2];
            float go = gbuf[192 + lid]  + xgv[3];
            float fi = sigm_(gi), ff = sigm_(gf), tc = tanhf(gc), fo = sigm_(go);
            float cn = ff * c_reg + fi * tc;
            c_reg = cn;
            float hn = fo * tanhf(cn);
            hbuf[((t + 1) & 1) * 12288 + bl * 768 + col] = hn;
            s[(size_t)(t * 16 + bl) * 768 + col] = resid ? (s_old + hn) : hn;
        }

        // ---- grid barrier (epoch = tloc+1; flags zeroed before launch) ----
        __syncthreads();   // all stores complete before release
        if (tid == 0) {
            __builtin_amdgcn_fence(__ATOMIC_RELEASE, "agent");
            const unsigned e = (unsigned)(tloc + 1);
            unsigned a = __hip_atomic_fetch_add(&flags[(bid >> 5) << 4], 1u,
                                                __ATOMIC_RELAXED, __HIP_MEMORY_SCOPE_AGENT);
            if (a == e * 32u - 1u) {
                unsigned r = __hip_atomic_fetch_add(&flags[96], 1u,
                                                    __ATOMIC_RELAXED, __HIP_MEMORY_SCOPE_AGENT);
                if (r == e * 6u - 1u)
                    __hip_atomic_store(&flags[112], e, __ATOMIC_RELEASE, __HIP_MEMORY_SCOPE_AGENT);
            }
            while (__hip_atomic_load(&flags[112], __ATOMIC_RELAXED, __HIP_MEMORY_SCOPE_AGENT) < e)
                __builtin_amdgcn_s_sleep(1);
        }
        __syncthreads();
        __builtin_amdgcn_fence(__ATOMIC_ACQUIRE, "agent");
    }

    if (g == 0) cbuf[bl * 768 + col] = c_reg;
}

// ---------------------------------------------------------------------------
extern "C" void kernel_launch(void* const* d_in, const int* in_sizes, int n_in,
                              void* d_out, int out_size, void* d_ws, size_t ws_size,
                              hipStream_t stream)
{
    const float* x    = (const float*)d_in[0];
    const float* mels = (const float*)d_in[1];
    const float* pw1  = (const float*)d_in[2];
    const float* pb1  = (const float*)d_in[3];
    const float* pw2  = (const float*)d_in[4];
    const float* pb2  = (const float*)d_in[5];
    const float* w_ih[3] = {(const float*)d_in[6],  (const float*)d_in[10], (const float*)d_in[14]};
    const float* w_hh[3] = {(const float*)d_in[7],  (const float*)d_in[11], (const float*)d_in[15]};
    const float* b_ih[3] = {(const float*)d_in[8],  (const float*)d_in[12], (const float*)d_in[16]};
    const float* b_hh[3] = {(const float*)d_in[9],  (const float*)d_in[13], (const float*)d_in[17]};
    const float* projw = (const float*)d_in[18];
    float* out = (float*)d_out;

    float* s    = (float*)d_ws;            // [1000][16][768]
    float* m2   = s + 12288000;            // [16000][256] (t,b)-rows
    float* xgb  = m2 + 4096000;            // [256][16][3072] chunk buffer
    float* hbuf = xgb + 12582912;          // [2][16][768]
    float* cbuf = hbuf + 24576;            // [16][768]
    unsigned* flags = (unsigned*)(cbuf + 12288);
    float* m1 = xgb;                       // prenet intermediate aliases xg buffer

    // PreNet
    gemm_tn<<<dim3(125, 2), 256, 0, stream>>>(mels, 128, 128000, pw1, 128, pb1, nullptr,
                                              m1, 4096, 256, 128, 1, 0);
    gemm_tn<<<dim3(125, 2), 256, 0, stream>>>(m1, 4096, 256, pw2, 256, pb2, nullptr,
                                              m2, 4096, 256, 256, 1, 0);

    const int t0s[4] = {0, 256, 512, 768};
    const int tcs[4] = {256, 256, 256, 232};

    for (int L = 0; L < 3; ++L) {
        hipMemsetAsync(hbuf, 0, (size_t)(24576 + 12288) * sizeof(float), stream);  // h=0, c=0
        for (int ch = 0; ch < 4; ++ch) {
            int t0 = t0s[ch], tc = tcs[ch];
            int gm = (tc * 16) / 128;  // 32 or 29
            if (L == 0) {
                gemm_tn<<<dim3(gm, 24), 256, 0, stream>>>(x + (size_t)t0 * 512, 512, 512000,
                                                          w_ih[0], 768, b_ih[0], b_hh[0],
                                                          xgb, 49152, 3072, 512, 0, 0);
                gemm_tn<<<dim3(gm, 24), 256, 0, stream>>>(m2 + (size_t)t0 * 4096, 4096, 256,
                                                          w_ih[0] + 512, 768, nullptr, nullptr,
                                                          xgb, 49152, 3072, 256, 0, 1);
            } else {
                gemm_tn<<<dim3(gm, 24), 256, 0, stream>>>(s + (size_t)t0 * 12288, 12288, 768,
                                                          w_ih[L], 768, b_ih[L], b_hh[L],
                                                          xgb, 49152, 3072, 768, 0, 0);
            }
            hipMemsetAsync(flags, 0, 512, stream);
            int t1 = t0 + tc;
            int resid = (L > 0) ? 1 : 0;
            lstm_scan<<<dim3(NBLK), 256, 0, stream>>>(xgb, s, hbuf, cbuf, w_hh[L], flags,
                                                      t0, t1, resid);
        }
    }

    // out[b][t][:] = s @ proj_w^T
    gemm_tn<<<dim3(125, 1), 256, 0, stream>>>(s, 12288, 768, projw, 768, nullptr, nullptr,
                                              out, 128, 128000, 768, 0, 0);
}

// Round 6
// 56222.546 us; speedup vs baseline: 1.0181x; 1.0119x over previous
//
#include <hip/hip_runtime.h>

// Decoder: PreNet(2xLinear+ReLU) -> 3x LSTM(768) with residuals -> proj(768->128)
// B=16, T=1000, H=768. All fp32.
//
//  - gemm_tn: fp32 C[M,N] = act(A @ W^T + b1 + b2 (+C)). 128x128 tile, BK=32,
//    8x8 reg tile, XOR-swizzled LDS (verified: bank-conflicts ~0 in round 5).
//  - lstm_scan: persistent kernel, 192 blocks x 256 thr. ZERO indexed arrays in
//    the hot loop: 16 named float4 accumulators (component = column) + 12 named
//    float4 W fragments; butterfly = component swaps + named-pair swaps.
//    (round 3/5 post-mortem: indexed arrays were demoted to scratch, VGPR=84.)
//  - xg per 256-step chunk.
//
// ws layout (floats): s[12288000] | m2[4096000] | xg[12582912] | hbuf[24576] | cbuf[12288] | flags

#define NBLK 192

// ---------------------------------------------------------------------------
// GEMM: C = act(A @ W^T + biases (+C)); A/C rows decoded as (t,b).
// LDS swizzle: logical (k, col) stored at [k][col ^ ((k>>2 & 7)<<2)], stride 128.
// ---------------------------------------------------------------------------
__global__ __launch_bounds__(256, 2) void gemm_tn(
    const float* __restrict__ A, int sa_t, int sa_b,
    const float* __restrict__ W, int ldw,
    const float* __restrict__ b1, const float* __restrict__ b2,
    float* __restrict__ C, int sc_t, int sc_b,
    int K, int relu, int beta)
{
    __shared__ __align__(16) float At[32][128];
    __shared__ __align__(16) float Wt[32][128];
    const int tid = threadIdx.x;
    const int bm = blockIdx.x << 7;
    const int bn = blockIdx.y << 7;
    const int tx = tid & 15, ty = tid >> 4;

    float acc[8][8];
#pragma unroll
    for (int i = 0; i < 8; ++i)
#pragma unroll
        for (int j = 0; j < 8; ++j) acc[i][j] = 0.f;

    const int row_s = tid >> 3;        // 0..31
    const int kq    = (tid & 7) << 2;  // 0,4,..,28
    const int qw    = kq >> 2;         // 0..7

    for (int k0 = 0; k0 < K; k0 += 32) {
#pragma unroll
        for (int i = 0; i < 4; ++i) {
            const int row = row_s + (i << 5);      // 0..127
            const int m = bm + row;
            const float* ap = A + (size_t)(m >> 4) * sa_t + (m & 15) * sa_b + k0 + kq;
            float4 av = *(const float4*)ap;
            const int n = bn + row;
            const float* wp = W + (size_t)n * ldw + k0 + kq;
            float4 wv = *(const float4*)wp;
            const int p = row ^ (qw << 2);         // swizzled column
            At[kq + 0][p] = av.x; At[kq + 1][p] = av.y;
            At[kq + 2][p] = av.z; At[kq + 3][p] = av.w;
            Wt[kq + 0][p] = wv.x; Wt[kq + 1][p] = wv.y;
            Wt[kq + 2][p] = wv.z; Wt[kq + 3][p] = wv.w;
        }
        __syncthreads();
#pragma unroll
        for (int kk = 0; kk < 32; ++kk) {
            const int sw = ((kk >> 2) & 7) << 2;
            float a[8], w[8];
            const int ab = (ty << 3) ^ sw;
            *(float4*)&a[0] = *(const float4*)&At[kk][ab];
            *(float4*)&a[4] = *(const float4*)&At[kk][ab ^ 4];
            const int wb = (tx << 2) ^ sw;
            *(float4*)&w[0] = *(const float4*)&Wt[kk][wb];
            *(float4*)&w[4] = *(const float4*)&Wt[kk][64 + wb];
#pragma unroll
            for (int i = 0; i < 8; ++i)
#pragma unroll
                for (int j = 0; j < 8; ++j) acc[i][j] += a[i] * w[j];
        }
        __syncthreads();
    }

#pragma unroll
    for (int i = 0; i < 8; ++i) {
        const int m = bm + (ty << 3) + i;
        const size_t crow = (size_t)(m >> 4) * sc_t + (m & 15) * sc_b;
#pragma unroll
        for (int jg = 0; jg < 2; ++jg) {
            const int n = bn + (jg << 6) + (tx << 2);
            const int j0 = jg << 2;
            float4 v = make_float4(acc[i][j0], acc[i][j0 + 1], acc[i][j0 + 2], acc[i][j0 + 3]);
            if (b1) { float4 t = *(const float4*)(b1 + n); v.x += t.x; v.y += t.y; v.z += t.z; v.w += t.w; }
            if (b2) { float4 t = *(const float4*)(b2 + n); v.x += t.x; v.y += t.y; v.z += t.z; v.w += t.w; }
            if (beta) { float4 t = *(const float4*)(C + crow + n); v.x += t.x; v.y += t.y; v.z += t.z; v.w += t.w; }
            if (relu) { v.x = fmaxf(v.x, 0.f); v.y = fmaxf(v.y, 0.f); v.z = fmaxf(v.z, 0.f); v.w = fmaxf(v.w, 0.f); }
            *(float4*)(C + crow + n) = v;
        }
    }
}

// ---------------------------------------------------------------------------
// LSTM scan (persistent). All-named registers: no indexed arrays anywhere.
// Accumulator Ab (b=0..15): component x/y/z/w = block column 0/1/2/3.
// v-index equivalence: v[c*16+b] == A{b}.{comp c}. Butterfly stage 32 pairs
// c<->c+2 (x<->z, y<->w), stage 16 pairs c<->c+1 (x<->y), stages 8..1 pair
// named variables b<->b^d. Lane l ends with full dot for (c=l>>4, b=l&15).
// ---------------------------------------------------------------------------
__device__ __forceinline__ float sigm_(float x) { return 1.f / (1.f + expf(-x)); }

#define DOT3(Wa,Wb,Wc) (Wa.x*h0.x + Wa.y*h0.y + Wa.z*h0.z + Wa.w*h0.w \
                      + Wb.x*h1.x + Wb.y*h1.y + Wb.z*h1.z + Wb.w*h1.w \
                      + Wc.x*h2.x + Wc.y*h2.y + Wc.z*h2.z + Wc.w*h2.w)

#define ACCB(Ab, b) do {                                                \
        const float* hp_ = h_lds + (b) * 768 + (lid << 2);              \
        float4 h0 = *(const float4*)hp_;                                \
        float4 h1 = *(const float4*)(hp_ + 256);                        \
        float4 h2 = *(const float4*)(hp_ + 512);                        \
        Ab.x += DOT3(W00, W01, W02);                                    \
        Ab.y += DOT3(W10, W11, W12);                                    \
        Ab.z += DOT3(W20, W21, W22);                                    \
        Ab.w += DOT3(W30, W31, W32);                                    \
    } while (0)

#define BF32(Ab) do {                                                   \
        float sx_ = (lid & 32) ? Ab.x : Ab.z;                           \
        float sy_ = (lid & 32) ? Ab.y : Ab.w;                           \
        float mx_ = (lid & 32) ? Ab.z : Ab.x;                           \
        float my_ = (lid & 32) ? Ab.w : Ab.y;                           \
        Ab.x = mx_ + __shfl_xor(sx_, 32, 64);                           \
        Ab.y = my_ + __shfl_xor(sy_, 32, 64);                           \
    } while (0)

#define BF16(Ab) do {                                                   \
        float s_ = (lid & 16) ? Ab.x : Ab.y;                            \
        float m_ = (lid & 16) ? Ab.y : Ab.x;                            \
        Ab.x = m_ + __shfl_xor(s_, 16, 64);                             \
    } while (0)

#define BFP(Alo, Ahi, d) do {                                           \
        float s_ = (lid & (d)) ? Alo.x : Ahi.x;                         \
        float m_ = (lid & (d)) ? Ahi.x : Alo.x;                         \
        Alo.x = m_ + __shfl_xor(s_, (d), 64);                           \
    } while (0)

__global__ __launch_bounds__(256, 1) void lstm_scan(
    const float* __restrict__ xg, float* __restrict__ s,
    float* __restrict__ hbuf, float* __restrict__ cbuf,
    const float* __restrict__ w_hh, unsigned* __restrict__ flags,
    int t0, int t1, int resid)
{
    __shared__ __align__(16) float h_lds[12288];   // [16][768]
    __shared__ __align__(16) float gbuf[256];
    const int tid = threadIdx.x;
    const int g   = tid >> 6;    // wave id = gate (i,f,g,o)
    const int lid = tid & 63;
    const int bid = blockIdx.x;
    const int col = (bid << 2) + (lid >> 4);  // wave-0 output column
    const int bl  = lid & 15;                 // wave-0 output batch

    // W rows (named): W{c}{q} = w_hh[g*768 + bid*4 + c][lid*4 + q*256 .. +3]
    const float* wr0 = w_hh + (size_t)(g * 768 + (bid << 2) + 0) * 768 + (lid << 2);
    const float* wr1 = w_hh + (size_t)(g * 768 + (bid << 2) + 1) * 768 + (lid << 2);
    const float* wr2 = w_hh + (size_t)(g * 768 + (bid << 2) + 2) * 768 + (lid << 2);
    const float* wr3 = w_hh + (size_t)(g * 768 + (bid << 2) + 3) * 768 + (lid << 2);
    float4 W00 = *(const float4*)(wr0);       float4 W01 = *(const float4*)(wr0 + 256); float4 W02 = *(const float4*)(wr0 + 512);
    float4 W10 = *(const float4*)(wr1);       float4 W11 = *(const float4*)(wr1 + 256); float4 W12 = *(const float4*)(wr1 + 512);
    float4 W20 = *(const float4*)(wr2);       float4 W21 = *(const float4*)(wr2 + 256); float4 W22 = *(const float4*)(wr2 + 512);
    float4 W30 = *(const float4*)(wr3);       float4 W31 = *(const float4*)(wr3 + 256); float4 W32 = *(const float4*)(wr3 + 512);

    float c_reg = 0.f;
    if (g == 0) c_reg = cbuf[bl * 768 + col];

    for (int t = t0; t < t1; ++t) {
        const int tloc = t - t0;

        // wave 0: issue xg / s_old loads early
        float xv0 = 0.f, xv1 = 0.f, xv2 = 0.f, xv3 = 0.f, s_old = 0.f;
        if (g == 0) {
            const float* xp = xg + (size_t)(tloc * 16 + bl) * 3072 + col;
            xv0 = xp[0]; xv1 = xp[768]; xv2 = xp[1536]; xv3 = xp[2304];
            if (resid) s_old = s[(size_t)(t * 16 + bl) * 768 + col];
        }

        // stage h (parity on absolute t) global -> LDS (direct-to-LDS DMA)
        const float* hin = hbuf + (t & 1) * 12288;
        {
            const int wv = tid >> 6;
#pragma unroll
            for (int i = 0; i < 12; ++i) {
                const float* gp = hin + (tid << 2) + (i << 10);     // per-lane global addr
                float* lp = h_lds + (wv << 8) + (i << 10);          // wave-uniform LDS base
                __builtin_amdgcn_global_load_lds(
                    (const __attribute__((address_space(1))) unsigned int*)gp,
                    (__attribute__((address_space(3))) unsigned int*)lp, 16, 0, 0);
            }
        }
        __syncthreads();   // drains vmcnt: LDS valid

        // named accumulators, zeroed each step
        float4 A0 = {0,0,0,0}, A1 = {0,0,0,0}, A2 = {0,0,0,0}, A3 = {0,0,0,0};
        float4 A4 = {0,0,0,0}, A5 = {0,0,0,0}, A6 = {0,0,0,0}, A7 = {0,0,0,0};
        float4 A8 = {0,0,0,0}, A9 = {0,0,0,0}, A10 = {0,0,0,0}, A11 = {0,0,0,0};
        float4 A12 = {0,0,0,0}, A13 = {0,0,0,0}, A14 = {0,0,0,0}, A15 = {0,0,0,0};

        ACCB(A0, 0);  ACCB(A1, 1);  ACCB(A2, 2);  ACCB(A3, 3);
        ACCB(A4, 4);  ACCB(A5, 5);  ACCB(A6, 6);  ACCB(A7, 7);
        ACCB(A8, 8);  ACCB(A9, 9);  ACCB(A10, 10); ACCB(A11, 11);
        ACCB(A12, 12); ACCB(A13, 13); ACCB(A14, 14); ACCB(A15, 15);

        // butterfly reduce-scatter (all static names)
        BF32(A0); BF32(A1); BF32(A2); BF32(A3); BF32(A4); BF32(A5); BF32(A6); BF32(A7);
        BF32(A8); BF32(A9); BF32(A10); BF32(A11); BF32(A12); BF32(A13); BF32(A14); BF32(A15);
        BF16(A0); BF16(A1); BF16(A2); BF16(A3); BF16(A4); BF16(A5); BF16(A6); BF16(A7);
        BF16(A8); BF16(A9); BF16(A10); BF16(A11); BF16(A12); BF16(A13); BF16(A14); BF16(A15);
        BFP(A0, A8, 8); BFP(A1, A9, 8); BFP(A2, A10, 8); BFP(A3, A11, 8);
        BFP(A4, A12, 8); BFP(A5, A13, 8); BFP(A6, A14, 8); BFP(A7, A15, 8);
        BFP(A0, A4, 4); BFP(A1, A5, 4); BFP(A2, A6, 4); BFP(A3, A7, 4);
        BFP(A0, A2, 2); BFP(A1, A3, 2);
        BFP(A0, A1, 1);

        gbuf[(g << 6) + lid] = A0.x;
        __syncthreads();

        if (g == 0) {
            float gi = gbuf[lid]       + xv0;
            float gf = gbuf[64 + lid]  + xv1;
            float gc = gbuf[128 + lid] + xv2;
            float go = gbuf[192 + lid] + xv3;
            float fi = sigm_(gi), ff = sigm_(gf), tc = tanhf(gc), fo = sigm_(go);
            float cn = ff * c_reg + fi * tc;
            c_reg = cn;
            float hn = fo * tanhf(cn);
            hbuf[((t + 1) & 1) * 12288 + bl * 768 + col] = hn;
            s[(size_t)(t * 16 + bl) * 768 + col] = resid ? (s_old + hn) : hn;
        }

        // ---- grid barrier (epoch = tloc+1; flags zeroed before launch) ----
        __syncthreads();   // all stores complete before release
        if (tid == 0) {
            __builtin_amdgcn_fence(__ATOMIC_RELEASE, "agent");
            const unsigned e = (unsigned)(tloc + 1);
            unsigned a = __hip_atomic_fetch_add(&flags[(bid >> 5) << 4], 1u,
                                                __ATOMIC_RELAXED, __HIP_MEMORY_SCOPE_AGENT);
            if (a == e * 32u - 1u) {
                unsigned r = __hip_atomic_fetch_add(&flags[96], 1u,
                                                    __ATOMIC_RELAXED, __HIP_MEMORY_SCOPE_AGENT);
                if (r == e * 6u - 1u)
                    __hip_atomic_store(&flags[112], e, __ATOMIC_RELEASE, __HIP_MEMORY_SCOPE_AGENT);
            }
            while (__hip_atomic_load(&flags[112], __ATOMIC_RELAXED, __HIP_MEMORY_SCOPE_AGENT) < e)
                __builtin_amdgcn_s_sleep(1);
        }
        __syncthreads();
        __builtin_amdgcn_fence(__ATOMIC_ACQUIRE, "agent");
    }

    if (g == 0) cbuf[bl * 768 + col] = c_reg;
}

// ---------------------------------------------------------------------------
extern "C" void kernel_launch(void* const* d_in, const int* in_sizes, int n_in,
                              void* d_out, int out_size, void* d_ws, size_t ws_size,
                              hipStream_t stream)
{
    const float* x    = (const float*)d_in[0];
    const float* mels = (const float*)d_in[1];
    const float* pw1  = (const float*)d_in[2];
    const float* pb1  = (const float*)d_in[3];
    const float* pw2  = (const float*)d_in[4];
    const float* pb2  = (const float*)d_in[5];
    const float* w_ih[3] = {(const float*)d_in[6],  (const float*)d_in[10], (const float*)d_in[14]};
    const float* w_hh[3] = {(const float*)d_in[7],  (const float*)d_in[11], (const float*)d_in[15]};
    const float* b_ih[3] = {(const float*)d_in[8],  (const float*)d_in[12], (const float*)d_in[16]};
    const float* b_hh[3] = {(const float*)d_in[9],  (const float*)d_in[13], (const float*)d_in[17]};
    const float* projw = (const float*)d_in[18];
    float* out = (float*)d_out;

    float* s    = (float*)d_ws;            // [1000][16][768]
    float* m2   = s + 12288000;            // [16000][256] (t,b)-rows
    float* xgb  = m2 + 4096000;            // [256][16][3072] chunk buffer
    float* hbuf = xgb + 12582912;          // [2][16][768]
    float* cbuf = hbuf + 24576;            // [16][768]
    unsigned* flags = (unsigned*)(cbuf + 12288);
    float* m1 = xgb;                       // prenet intermediate aliases xg buffer

    // PreNet
    gemm_tn<<<dim3(125, 2), 256, 0, stream>>>(mels, 128, 128000, pw1, 128, pb1, nullptr,
                                              m1, 4096, 256, 128, 1, 0);
    gemm_tn<<<dim3(125, 2), 256, 0, stream>>>(m1, 4096, 256, pw2, 256, pb2, nullptr,
                                              m2, 4096, 256, 256, 1, 0);

    const int t0s[4] = {0, 256, 512, 768};
    const int tcs[4] = {256, 256, 256, 232};

    for (int L = 0; L < 3; ++L) {
        hipMemsetAsync(hbuf, 0, (size_t)(24576 + 12288) * sizeof(float), stream);  // h=0, c=0
        for (int ch = 0; ch < 4; ++ch) {
            int t0 = t0s[ch], tc = tcs[ch];
            int gm = (tc * 16) / 128;  // 32 or 29
            if (L == 0) {
                gemm_tn<<<dim3(gm, 24), 256, 0, stream>>>(x + (size_t)t0 * 512, 512, 512000,
                                                          w_ih[0], 768, b_ih[0], b_hh[0],
                                                          xgb, 49152, 3072, 512, 0, 0);
                gemm_tn<<<dim3(gm, 24), 256, 0, stream>>>(m2 + (size_t)t0 * 4096, 4096, 256,
                                                          w_ih[0] + 512, 768, nullptr, nullptr,
                                                          xgb, 49152, 3072, 256, 0, 1);
            } else {
                gemm_tn<<<dim3(gm, 24), 256, 0, stream>>>(s + (size_t)t0 * 12288, 12288, 768,
                                                          w_ih[L], 768, b_ih[L], b_hh[L],
                                                          xgb, 49152, 3072, 768, 0, 0);
            }
            hipMemsetAsync(flags, 0, 512, stream);
            int t1 = t0 + tc;
            int resid = (L > 0) ? 1 : 0;
            lstm_scan<<<dim3(NBLK), 256, 0, stream>>>(xgb, s, hbuf, cbuf, w_hh[L], flags,
                                                      t0, t1, resid);
        }
    }

    // out[b][t][:] = s @ proj_w^T
    gemm_tn<<<dim3(125, 1), 256, 0, stream>>>(s, 12288, 768, projw, 768, nullptr, nullptr,
                                              out, 128, 128000, 768, 0, 0);
}

// Round 7
// 21462.183 us; speedup vs baseline: 2.6670x; 2.6196x over previous
//
#include <hip/hip_runtime.h>

// Decoder: PreNet(2xLinear+ReLU) -> 3x LSTM(768) with residuals -> proj(768->128)
// B=16, T=1000, H=768. All fp32.
//
//  - gemm_tn: fp32 tiled GEMM, XOR-swizzled LDS (verified ~0 bank conflicts, r5).
//  - lstm_scan: persistent, 192 blocks x 256 thr. FENCE-FREE cross-block protocol:
//    all h-exchange + barrier flags use sc0 sc1 (L1/L2-bypass, LLC-coherent) loads/
//    stores via inline asm; barrier = arrival words (one per block) + hub (block 0
//    wave 0) scans 192 words and publishes a release word. No agent fences, no
//    atomic contention, L2 stays warm for xg. (r6 post-mortem: the old fenced
//    atomic-tree barrier + per-wave acquire fences cost ~15us/step = 92% idle.)
//  - xg per 256-step chunk.
//
// ws layout (floats): s[12288000] | m2[4096000] | xg[12582912] | hbuf[24576] | cbuf[12288] | flags

#define NBLK 192

// ---------------------------------------------------------------------------
// GEMM: C = act(A @ W^T + biases (+C)); A/C rows decoded as (t,b).
// LDS swizzle: logical (k, col) stored at [k][col ^ ((k>>2 & 7)<<2)], stride 128.
// ---------------------------------------------------------------------------
__global__ __launch_bounds__(256, 2) void gemm_tn(
    const float* __restrict__ A, int sa_t, int sa_b,
    const float* __restrict__ W, int ldw,
    const float* __restrict__ b1, const float* __restrict__ b2,
    float* __restrict__ C, int sc_t, int sc_b,
    int K, int relu, int beta)
{
    __shared__ __align__(16) float At[32][128];
    __shared__ __align__(16) float Wt[32][128];
    const int tid = threadIdx.x;
    const int bm = blockIdx.x << 7;
    const int bn = blockIdx.y << 7;
    const int tx = tid & 15, ty = tid >> 4;

    float acc[8][8];
#pragma unroll
    for (int i = 0; i < 8; ++i)
#pragma unroll
        for (int j = 0; j < 8; ++j) acc[i][j] = 0.f;

    const int row_s = tid >> 3;
    const int kq    = (tid & 7) << 2;
    const int qw    = kq >> 2;

    for (int k0 = 0; k0 < K; k0 += 32) {
#pragma unroll
        for (int i = 0; i < 4; ++i) {
            const int row = row_s + (i << 5);
            const int m = bm + row;
            const float* ap = A + (size_t)(m >> 4) * sa_t + (m & 15) * sa_b + k0 + kq;
            float4 av = *(const float4*)ap;
            const int n = bn + row;
            const float* wp = W + (size_t)n * ldw + k0 + kq;
            float4 wv = *(const float4*)wp;
            const int p = row ^ (qw << 2);
            At[kq + 0][p] = av.x; At[kq + 1][p] = av.y;
            At[kq + 2][p] = av.z; At[kq + 3][p] = av.w;
            Wt[kq + 0][p] = wv.x; Wt[kq + 1][p] = wv.y;
            Wt[kq + 2][p] = wv.z; Wt[kq + 3][p] = wv.w;
        }
        __syncthreads();
#pragma unroll
        for (int kk = 0; kk < 32; ++kk) {
            const int sw = ((kk >> 2) & 7) << 2;
            float a[8], w[8];
            const int ab = (ty << 3) ^ sw;
            *(float4*)&a[0] = *(const float4*)&At[kk][ab];
            *(float4*)&a[4] = *(const float4*)&At[kk][ab ^ 4];
            const int wb = (tx << 2) ^ sw;
            *(float4*)&w[0] = *(const float4*)&Wt[kk][wb];
            *(float4*)&w[4] = *(const float4*)&Wt[kk][64 + wb];
#pragma unroll
            for (int i = 0; i < 8; ++i)
#pragma unroll
                for (int j = 0; j < 8; ++j) acc[i][j] += a[i] * w[j];
        }
        __syncthreads();
    }

#pragma unroll
    for (int i = 0; i < 8; ++i) {
        const int m = bm + (ty << 3) + i;
        const size_t crow = (size_t)(m >> 4) * sc_t + (m & 15) * sc_b;
#pragma unroll
        for (int jg = 0; jg < 2; ++jg) {
            const int n = bn + (jg << 6) + (tx << 2);
            const int j0 = jg << 2;
            float4 v = make_float4(acc[i][j0], acc[i][j0 + 1], acc[i][j0 + 2], acc[i][j0 + 3]);
            if (b1) { float4 t = *(const float4*)(b1 + n); v.x += t.x; v.y += t.y; v.z += t.z; v.w += t.w; }
            if (b2) { float4 t = *(const float4*)(b2 + n); v.x += t.x; v.y += t.y; v.z += t.z; v.w += t.w; }
            if (beta) { float4 t = *(const float4*)(C + crow + n); v.x += t.x; v.y += t.y; v.z += t.z; v.w += t.w; }
            if (relu) { v.x = fmaxf(v.x, 0.f); v.y = fmaxf(v.y, 0.f); v.z = fmaxf(v.z, 0.f); v.w = fmaxf(v.w, 0.f); }
            *(float4*)(C + crow + n) = v;
        }
    }
}

// ---------------------------------------------------------------------------
// LLC-coherent (L1+L2-bypassing) memory ops. sc0 sc1 => operate at the device
// coherence point (LLC), which IS coherent across XCDs. No fences needed.
// ---------------------------------------------------------------------------
__device__ __forceinline__ float4 ld_f4_llc(const float* p) {
    float4 r;
    asm volatile("global_load_dwordx4 %0, %1, off sc0 sc1" : "=v"(r) : "v"(p) : "memory");
    return r;
}
__device__ __forceinline__ uint4 ld_u4_llc_wait(const unsigned* p) {
    uint4 r;
    asm volatile("global_load_dwordx4 %0, %1, off sc0 sc1\n\ts_waitcnt vmcnt(0)"
                 : "=v"(r) : "v"(p) : "memory");
    return r;
}
__device__ __forceinline__ unsigned ld_u32_llc_wait(const unsigned* p) {
    unsigned r;
    asm volatile("global_load_dword %0, %1, off sc0 sc1\n\ts_waitcnt vmcnt(0)"
                 : "=v"(r) : "v"(p) : "memory");
    return r;
}
__device__ __forceinline__ void st_f32_llc(float* p, float v) {
    asm volatile("global_store_dword %0, %1, off sc0 sc1" :: "v"(p), "v"(v) : "memory");
}
__device__ __forceinline__ void st_u32_llc(unsigned* p, unsigned v) {
    asm volatile("global_store_dword %0, %1, off sc0 sc1" :: "v"(p), "v"(v) : "memory");
}

// ---------------------------------------------------------------------------
// LSTM scan (persistent, fence-free). All-named registers (r6 structure).
// ---------------------------------------------------------------------------
__device__ __forceinline__ float sigm_(float x) { return 1.f / (1.f + expf(-x)); }

#define DOT3(Wa,Wb,Wc) (Wa.x*h0.x + Wa.y*h0.y + Wa.z*h0.z + Wa.w*h0.w \
                      + Wb.x*h1.x + Wb.y*h1.y + Wb.z*h1.z + Wb.w*h1.w \
                      + Wc.x*h2.x + Wc.y*h2.y + Wc.z*h2.z + Wc.w*h2.w)

#define ACCB(Ab, b) do {                                                \
        const float* hp_ = h_lds + (b) * 768 + (lid << 2);              \
        float4 h0 = *(const float4*)hp_;                                \
        float4 h1 = *(const float4*)(hp_ + 256);                        \
        float4 h2 = *(const float4*)(hp_ + 512);                        \
        Ab.x += DOT3(W00, W01, W02);                                    \
        Ab.y += DOT3(W10, W11, W12);                                    \
        Ab.z += DOT3(W20, W21, W22);                                    \
        Ab.w += DOT3(W30, W31, W32);                                    \
    } while (0)

#define BF32(Ab) do {                                                   \
        float sx_ = (lid & 32) ? Ab.x : Ab.z;                           \
        float sy_ = (lid & 32) ? Ab.y : Ab.w;                           \
        float mx_ = (lid & 32) ? Ab.z : Ab.x;                           \
        float my_ = (lid & 32) ? Ab.w : Ab.y;                           \
        Ab.x = mx_ + __shfl_xor(sx_, 32, 64);                           \
        Ab.y = my_ + __shfl_xor(sy_, 32, 64);                           \
    } while (0)

#define BF16(Ab) do {                                                   \
        float s_ = (lid & 16) ? Ab.x : Ab.y;                            \
        float m_ = (lid & 16) ? Ab.y : Ab.x;                            \
        Ab.x = m_ + __shfl_xor(s_, 16, 64);                             \
    } while (0)

#define BFP(Alo, Ahi, d) do {                                           \
        float s_ = (lid & (d)) ? Alo.x : Ahi.x;                         \
        float m_ = (lid & (d)) ? Ahi.x : Alo.x;                         \
        Alo.x = m_ + __shfl_xor(s_, (d), 64);                           \
    } while (0)

#define LDH(i) float4 hv##i = ld_f4_llc(hin + (i) * 1024)
#define STH(i) lb[(i) * 256] = hv##i

__global__ __launch_bounds__(256, 1) void lstm_scan(
    const float* __restrict__ xg, float* __restrict__ s,
    float* __restrict__ hbuf, float* __restrict__ cbuf,
    const float* __restrict__ w_hh, unsigned* __restrict__ flags,
    int t0, int t1, int resid)
{
    __shared__ __align__(16) float h_lds[12288];   // [16][768]
    __shared__ __align__(16) float gbuf[256];
    const int tid = threadIdx.x;
    const int g   = tid >> 6;    // wave id = gate (i,f,g,o)
    const int lid = tid & 63;
    const int bid = blockIdx.x;
    const int col = (bid << 2) + (lid >> 4);  // wave-0 output column
    const int bl  = lid & 15;                 // wave-0 output batch

    // W rows (named): W{c}{q} = w_hh[g*768 + bid*4 + c][lid*4 + q*256 .. +3]
    const float* wr0 = w_hh + (size_t)(g * 768 + (bid << 2) + 0) * 768 + (lid << 2);
    const float* wr1 = w_hh + (size_t)(g * 768 + (bid << 2) + 1) * 768 + (lid << 2);
    const float* wr2 = w_hh + (size_t)(g * 768 + (bid << 2) + 2) * 768 + (lid << 2);
    const float* wr3 = w_hh + (size_t)(g * 768 + (bid << 2) + 3) * 768 + (lid << 2);
    float4 W00 = *(const float4*)(wr0);       float4 W01 = *(const float4*)(wr0 + 256); float4 W02 = *(const float4*)(wr0 + 512);
    float4 W10 = *(const float4*)(wr1);       float4 W11 = *(const float4*)(wr1 + 256); float4 W12 = *(const float4*)(wr1 + 512);
    float4 W20 = *(const float4*)(wr2);       float4 W21 = *(const float4*)(wr2 + 256); float4 W22 = *(const float4*)(wr2 + 512);
    float4 W30 = *(const float4*)(wr3);       float4 W31 = *(const float4*)(wr3 + 256); float4 W32 = *(const float4*)(wr3 + 512);

    float c_reg = 0.f;
    if (g == 0) c_reg = cbuf[bl * 768 + col];

    for (int t = t0; t < t1; ++t) {
        const unsigned e = (unsigned)(t - t0 + 1);

        // wave 0: issue xg / s_old loads early (normal cached; L2 stays warm now)
        float xv0 = 0.f, xv1 = 0.f, xv2 = 0.f, xv3 = 0.f, s_old = 0.f;
        if (g == 0) {
            const float* xp = xg + (size_t)((t - t0) * 16 + bl) * 3072 + col;
            xv0 = xp[0]; xv1 = xp[768]; xv2 = xp[1536]; xv3 = xp[2304];
            if (resid) s_old = s[(size_t)(t * 16 + bl) * 768 + col];
        }

        // stage h: 12x LLC loads (bypass stale L1/L2) -> regs -> LDS
        const float* hin = hbuf + (t & 1) * 12288 + (tid << 2);
        LDH(0); LDH(1); LDH(2); LDH(3); LDH(4); LDH(5);
        LDH(6); LDH(7); LDH(8); LDH(9); LDH(10); LDH(11);
        asm volatile("s_waitcnt vmcnt(0)" ::: "memory");
        __builtin_amdgcn_sched_barrier(0);
        {
            float4* lb = (float4*)h_lds + tid;
            STH(0); STH(1); STH(2); STH(3); STH(4); STH(5);
            STH(6); STH(7); STH(8); STH(9); STH(10); STH(11);
        }
        __syncthreads();

        // named accumulators
        float4 A0 = {0,0,0,0}, A1 = {0,0,0,0}, A2 = {0,0,0,0}, A3 = {0,0,0,0};
        float4 A4 = {0,0,0,0}, A5 = {0,0,0,0}, A6 = {0,0,0,0}, A7 = {0,0,0,0};
        float4 A8 = {0,0,0,0}, A9 = {0,0,0,0}, A10 = {0,0,0,0}, A11 = {0,0,0,0};
        float4 A12 = {0,0,0,0}, A13 = {0,0,0,0}, A14 = {0,0,0,0}, A15 = {0,0,0,0};

        ACCB(A0, 0);  ACCB(A1, 1);  ACCB(A2, 2);  ACCB(A3, 3);
        ACCB(A4, 4);  ACCB(A5, 5);  ACCB(A6, 6);  ACCB(A7, 7);
        ACCB(A8, 8);  ACCB(A9, 9);  ACCB(A10, 10); ACCB(A11, 11);
        ACCB(A12, 12); ACCB(A13, 13); ACCB(A14, 14); ACCB(A15, 15);

        BF32(A0); BF32(A1); BF32(A2); BF32(A3); BF32(A4); BF32(A5); BF32(A6); BF32(A7);
        BF32(A8); BF32(A9); BF32(A10); BF32(A11); BF32(A12); BF32(A13); BF32(A14); BF32(A15);
        BF16(A0); BF16(A1); BF16(A2); BF16(A3); BF16(A4); BF16(A5); BF16(A6); BF16(A7);
        BF16(A8); BF16(A9); BF16(A10); BF16(A11); BF16(A12); BF16(A13); BF16(A14); BF16(A15);
        BFP(A0, A8, 8); BFP(A1, A9, 8); BFP(A2, A10, 8); BFP(A3, A11, 8);
        BFP(A4, A12, 8); BFP(A5, A13, 8); BFP(A6, A14, 8); BFP(A7, A15, 8);
        BFP(A0, A4, 4); BFP(A1, A5, 4); BFP(A2, A6, 4); BFP(A3, A7, 4);
        BFP(A0, A2, 2); BFP(A1, A3, 2);
        BFP(A0, A1, 1);

        gbuf[(g << 6) + lid] = A0.x;
        __syncthreads();

        if (g == 0) {
            float gi = gbuf[lid]       + xv0;
            float gf = gbuf[64 + lid]  + xv1;
            float gc = gbuf[128 + lid] + xv2;
            float go = gbuf[192 + lid] + xv3;
            float fi = sigm_(gi), ff = sigm_(gf), tc = tanhf(gc), fo = sigm_(go);
            float cn = ff * c_reg + fi * tc;
            c_reg = cn;
            float hn = fo * tanhf(cn);
            // publish h for next step: write-through to LLC (no fence needed)
            st_f32_llc(hbuf + ((t + 1) & 1) * 12288 + bl * 768 + col, hn);
            s[(size_t)(t * 16 + bl) * 768 + col] = resid ? (s_old + hn) : hn;  // normal (next dispatch)

            // wait until our wave's h stores are globally visible, then arrive
            asm volatile("s_waitcnt vmcnt(0)" ::: "memory");
            if (lid == 0) st_u32_llc(flags + bid, e);

            if (bid == 0) {
                // hub: wave 0 of block 0 scans all 192 arrival words
                unsigned ok;
                do {
                    ok = 1u;
                    if (lid < 48) {
                        uint4 a = ld_u4_llc_wait(flags + (lid << 2));
                        ok = (a.x >= e) && (a.y >= e) && (a.z >= e) && (a.w >= e);
                    }
                } while (!__all(ok));
                if (lid == 0) st_u32_llc(flags + 256, e);   // release
            } else if (lid == 0) {
                while (ld_u32_llc_wait(flags + 256) < e) { }
            }
        }
        __syncthreads();   // whole block released once its wave 0 saw the flag
    }

    if (g == 0) cbuf[bl * 768 + col] = c_reg;
}

// ---------------------------------------------------------------------------
extern "C" void kernel_launch(void* const* d_in, const int* in_sizes, int n_in,
                              void* d_out, int out_size, void* d_ws, size_t ws_size,
                              hipStream_t stream)
{
    const float* x    = (const float*)d_in[0];
    const float* mels = (const float*)d_in[1];
    const float* pw1  = (const float*)d_in[2];
    const float* pb1  = (const float*)d_in[3];
    const float* pw2  = (const float*)d_in[4];
    const float* pb2  = (const float*)d_in[5];
    const float* w_ih[3] = {(const float*)d_in[6],  (const float*)d_in[10], (const float*)d_in[14]};
    const float* w_hh[3] = {(const float*)d_in[7],  (const float*)d_in[11], (const float*)d_in[15]};
    const float* b_ih[3] = {(const float*)d_in[8],  (const float*)d_in[12], (const float*)d_in[16]};
    const float* b_hh[3] = {(const float*)d_in[9],  (const float*)d_in[13], (const float*)d_in[17]};
    const float* projw = (const float*)d_in[18];
    float* out = (float*)d_out;

    float* s    = (float*)d_ws;            // [1000][16][768]
    float* m2   = s + 12288000;            // [16000][256] (t,b)-rows
    float* xgb  = m2 + 4096000;            // [256][16][3072] chunk buffer
    float* hbuf = xgb + 12582912;          // [2][16][768]
    float* cbuf = hbuf + 24576;            // [16][768]
    unsigned* flags = (unsigned*)(cbuf + 12288);  // arr[192] @0, release @ flags[256]
    float* m1 = xgb;                       // prenet intermediate aliases xg buffer

    // PreNet
    gemm_tn<<<dim3(125, 2), 256, 0, stream>>>(mels, 128, 128000, pw1, 128, pb1, nullptr,
                                              m1, 4096, 256, 128, 1, 0);
    gemm_tn<<<dim3(125, 2), 256, 0, stream>>>(m1, 4096, 256, pw2, 256, pb2, nullptr,
                                              m2, 4096, 256, 256, 1, 0);

    const int t0s[4] = {0, 256, 512, 768};
    const int tcs[4] = {256, 256, 256, 232};

    for (int L = 0; L < 3; ++L) {
        hipMemsetAsync(hbuf, 0, (size_t)(24576 + 12288) * sizeof(float), stream);  // h=0, c=0
        for (int ch = 0; ch < 4; ++ch) {
            int t0 = t0s[ch], tc = tcs[ch];
            int gm = (tc * 16) / 128;  // 32 or 29
            if (L == 0) {
                gemm_tn<<<dim3(gm, 24), 256, 0, stream>>>(x + (size_t)t0 * 512, 512, 512000,
                                                          w_ih[0], 768, b_ih[0], b_hh[0],
                                                          xgb, 49152, 3072, 512, 0, 0);
                gemm_tn<<<dim3(gm, 24), 256, 0, stream>>>(m2 + (size_t)t0 * 4096, 4096, 256,
                                                          w_ih[0] + 512, 768, nullptr, nullptr,
                                                          xgb, 49152, 3072, 256, 0, 1);
            } else {
                gemm_tn<<<dim3(gm, 24), 256, 0, stream>>>(s + (size_t)t0 * 12288, 12288, 768,
                                                          w_ih[L], 768, b_ih[L], b_hh[L],
                                                          xgb, 49152, 3072, 768, 0, 0);
            }
            hipMemsetAsync(flags, 0, 2048, stream);
            int t1 = t0 + tc;
            int resid = (L > 0) ? 1 : 0;
            lstm_scan<<<dim3(NBLK), 256, 0, stream>>>(xgb, s, hbuf, cbuf, w_hh[L], flags,
                                                      t0, t1, resid);
        }
    }

    // out[b][t][:] = s @ proj_w^T
    gemm_tn<<<dim3(125, 1), 256, 0, stream>>>(s, 12288, 768, projw, 768, nullptr, nullptr,
                                              out, 128, 128000, 768, 0, 0);
}